// Round 2
// baseline (55.238 us; speedup 1.0000x reference)
//
#include <hip/hip_runtime.h>
#include <hip/hip_bf16.h>

#define N_NODES 4096
#define IN_FEAT 128
#define OUT_FEAT 64
#define NHEAD 4
#define HID 256           // NHEAD * OUT_FEAT
#define NEG_SLOPE 0.2f
#define MAXC 256          // per-node neighbor cap (expected max degree ~75)
#define GEMM_BLOCKS 256   // 16 rows each

// ---------------------------------------------------------------------------
// Kernel 1 (fused): blocks 0..255 do h = x@W + attn_src/tgt reductions
// (no LDS: x read via block-uniform float4 loads -> scalar/L1-broadcast);
// blocks 256..4351 stream adj rows and write compacted neighbor lists.
// GEMM blocks are dispatched first so they overlap the adj HBM stream.
// ---------------------------------------------------------------------------
__global__ __launch_bounds__(256) void k_prep(
    const float* __restrict__ x, const float* __restrict__ adj,
    const float* __restrict__ W, const float* __restrict__ a,
    float* __restrict__ h, float* __restrict__ attn_src,
    float* __restrict__ attn_tgt,
    unsigned short* __restrict__ nbrs, int* __restrict__ deg)
{
    const int t = threadIdx.x;

    if (blockIdx.x < GEMM_BLOCKS) {
        // ---- GEMM part: 16 rows, column c = t ----
        const int row0 = blockIdx.x * 16;
        const int c = t;
        float acc[16];
        #pragma unroll
        for (int r = 0; r < 16; ++r) acc[r] = 0.f;

        for (int k = 0; k < IN_FEAT; k += 4) {
            const float w0 = W[(k + 0) * HID + c];   // coalesced, L2-resident
            const float w1 = W[(k + 1) * HID + c];
            const float w2 = W[(k + 2) * HID + c];
            const float w3 = W[(k + 3) * HID + c];
            #pragma unroll
            for (int r = 0; r < 16; ++r) {
                // block-uniform address -> scalar load (or L1 broadcast)
                const float4 xv = *reinterpret_cast<const float4*>(
                    x + (row0 + r) * IN_FEAT + k);
                acc[r] += xv.x * w0 + xv.y * w1 + xv.z * w2 + xv.w * w3;
            }
        }

        // Fused attn reductions: wave w == head w (c = head*64 + lane).
        const int lane = t & 63;
        const int head = t >> 6;
        const float asrc = a[head * (2 * OUT_FEAT) + lane];
        const float atgt = a[head * (2 * OUT_FEAT) + OUT_FEAT + lane];
        #pragma unroll
        for (int r = 0; r < 16; ++r) {
            float s = acc[r] * asrc;
            float g = acc[r] * atgt;
            #pragma unroll
            for (int d = 32; d; d >>= 1) {
                s += __shfl_xor(s, d, 64);
                g += __shfl_xor(g, d, 64);
            }
            if (lane == 0) {
                attn_src[(row0 + r) * NHEAD + head] = s;
                attn_tgt[(row0 + r) * NHEAD + head] = g;
            }
            h[(size_t)(row0 + r) * HID + c] = acc[r];
        }
    } else {
        // ---- adj scan part: node i, build neighbor list (+ self loop) ----
        __shared__ int wsum[4];
        const int i = blockIdx.x - GEMM_BLOCKS;
        const int lane = t & 63;
        const int wv = t >> 6;

        const float4* arow = reinterpret_cast<const float4*>(adj + (size_t)i * N_NODES);
        unsigned mask16 = 0;
        #pragma unroll
        for (int u = 0; u < 4; ++u) {
            float4 v = arow[u * 256 + t];
            int jb = u * 1024 + t * 4;
            if (v.x != 0.f || (jb + 0) == i) mask16 |= 1u << (u * 4 + 0);
            if (v.y != 0.f || (jb + 1) == i) mask16 |= 1u << (u * 4 + 1);
            if (v.z != 0.f || (jb + 2) == i) mask16 |= 1u << (u * 4 + 2);
            if (v.w != 0.f || (jb + 3) == i) mask16 |= 1u << (u * 4 + 3);
        }
        int cnt = __popc(mask16);

        // exclusive prefix over 256 threads
        int incl = cnt;
        #pragma unroll
        for (int d = 1; d < 64; d <<= 1) {
            int u2 = __shfl_up(incl, d, 64);
            if (lane >= d) incl += u2;
        }
        if (lane == 63) wsum[wv] = incl;
        __syncthreads();
        int base = 0;
        #pragma unroll
        for (int w = 0; w < 4; ++w) base += (w < wv) ? wsum[w] : 0;
        int total = wsum[0] + wsum[1] + wsum[2] + wsum[3];
        if (total > MAXC) total = MAXC;   // safety; cannot trip at 1% density
        int off = base + incl - cnt;

        unsigned m = mask16;
        unsigned short* nl = nbrs + (size_t)i * MAXC;
        while (m) {
            int b = __ffs((int)m) - 1;
            m &= m - 1;
            int j = ((b >> 2) * 1024) + t * 4 + (b & 3);
            if (off < MAXC) nl[off] = (unsigned short)j;
            ++off;
        }
        if (t == 0) deg[i] = total;
    }
}

// ---------------------------------------------------------------------------
// Kernel 2: per node i — softmax over neighbor list + aggregation.
// Wave wv owns head wv. Stage C processes 4 neighbors/iter:
// lane = g*16 + f4  (g: neighbor sub-slot, f4: float4 feature chunk).
// ---------------------------------------------------------------------------
__global__ __launch_bounds__(256) void k_agg(
    const unsigned short* __restrict__ nbrs, const int* __restrict__ deg,
    const float* __restrict__ h, const float* __restrict__ attn_src,
    const float* __restrict__ attn_tgt, float* __restrict__ out)
{
    __shared__ float p[NHEAD][MAXC];
    __shared__ unsigned short nl[MAXC];

    const int i = blockIdx.x;
    const int t = threadIdx.x;
    const int lane = t & 63;
    const int head = t >> 6;

    const int d = deg[i];
    nl[t] = (t < d) ? nbrs[(size_t)i * MAXC + t] : (unsigned short)0;
    __syncthreads();

    // ---- softmax (wave-local per head) ----
    const float srcv = attn_src[i * NHEAD + head];
    const int rnd = (d + 3) & ~3;
    float lmax = -1e30f;
    for (int idx = lane; idx < rnd; idx += 64) {
        if (idx < d) {
            float e = srcv + attn_tgt[nl[idx] * NHEAD + head];
            e = (e > 0.f) ? e : NEG_SLOPE * e;
            p[head][idx] = e;
            lmax = fmaxf(lmax, e);
        } else {
            p[head][idx] = 0.f;   // padding consumed with weight 0 below
        }
    }
    #pragma unroll
    for (int s = 32; s; s >>= 1) lmax = fmaxf(lmax, __shfl_xor(lmax, s, 64));
    float ssum = 0.f;
    for (int idx = lane; idx < d; idx += 64) {
        float pe = __expf(p[head][idx] - lmax);
        p[head][idx] = pe;
        ssum += pe;
    }
    #pragma unroll
    for (int s = 32; s; s >>= 1) ssum += __shfl_xor(ssum, s, 64);
    const float inv = 1.0f / ssum;   // d >= 1 always (self loop)

    // ---- aggregation: 4 neighbors per iteration ----
    const int g  = lane >> 4;        // neighbor sub-slot 0..3
    const int f4 = lane & 15;        // float4 feature chunk 0..15
    const float* hbase = h + head * OUT_FEAT + f4 * 4;
    float4 acc = {0.f, 0.f, 0.f, 0.f};
    for (int idx4 = 0; idx4 < d; idx4 += 4) {
        const int j   = nl[idx4 + g];          // LDS broadcast (pad -> 0)
        const float pw = p[head][idx4 + g];    // pad -> 0
        const float4 hv = *reinterpret_cast<const float4*>(hbase + (size_t)j * HID);
        acc.x += pw * hv.x; acc.y += pw * hv.y;
        acc.z += pw * hv.z; acc.w += pw * hv.w;
    }
    // reduce across the 4 neighbor sub-slots (lanes xor 16, 32)
    #pragma unroll
    for (int s = 16; s <= 32; s <<= 1) {
        acc.x += __shfl_xor(acc.x, s, 64);
        acc.y += __shfl_xor(acc.y, s, 64);
        acc.z += __shfl_xor(acc.z, s, 64);
        acc.w += __shfl_xor(acc.w, s, 64);
    }
    if (g == 0) {
        float4 o = {acc.x * inv, acc.y * inv, acc.z * inv, acc.w * inv};
        *reinterpret_cast<float4*>(out + (size_t)i * HID + head * OUT_FEAT + f4 * 4) = o;
    }
}

// ---------------------------------------------------------------------------
extern "C" void kernel_launch(void* const* d_in, const int* in_sizes, int n_in,
                              void* d_out, int out_size, void* d_ws, size_t ws_size,
                              hipStream_t stream)
{
    const float* x   = (const float*)d_in[0];   // (4096,128)
    const float* adj = (const float*)d_in[1];   // (4096,4096)
    const float* W   = (const float*)d_in[2];   // (128,256)
    const float* a   = (const float*)d_in[3];   // (4,128)
    float* out = (float*)d_out;                 // (4096,256)

    char* ws = (char*)d_ws;
    float* h         = (float*)ws;                                  // 4 MB
    float* attn_src  = (float*)(ws + (size_t)N_NODES * HID * 4);    // 64 KB
    float* attn_tgt  = attn_src + (size_t)N_NODES * NHEAD;          // 64 KB
    unsigned short* nbrs = (unsigned short*)(attn_tgt + (size_t)N_NODES * NHEAD); // 2 MB
    int* deg         = (int*)(nbrs + (size_t)N_NODES * MAXC);       // 16 KB

    k_prep<<<GEMM_BLOCKS + N_NODES, 256, 0, stream>>>(
        x, adj, W, a, h, attn_src, attn_tgt, nbrs, deg);
    k_agg<<<N_NODES, 256, 0, stream>>>(nbrs, deg, h, attn_src, attn_tgt, out);
}

// Round 3
// 36.144 us; speedup vs baseline: 1.5282x; 1.5282x over previous
//
#include <hip/hip_runtime.h>
#include <hip/hip_bf16.h>

#define N_NODES 4096
#define IN_FEAT 128
#define OUT_FEAT 64
#define NHEAD 4
#define HID 256           // NHEAD * OUT_FEAT
#define NEG_SLOPE 0.2f
#define MAXC 256          // per-node neighbor cap (expected max degree ~75)
#define GEMM_BLOCKS 256   // 64 row-blocks x 4 col-blocks (64x64 output tiles)

typedef float f4 __attribute__((ext_vector_type(4)));

// ---------------------------------------------------------------------------
// Kernel 1 (heterogeneous): blocks 0..255 = register-tiled GEMM (64x64 tile,
// 4x4 per thread) + fused attn_src/tgt reductions; blocks 256..4351 stream
// adj rows into compacted neighbor lists. GEMM blocks dispatch first (1/CU),
// scan blocks co-reside (34KB LDS -> ~3 scan blocks/CU) and overlap.
// ---------------------------------------------------------------------------
__global__ __launch_bounds__(256) void k_prep(
    const float* __restrict__ x, const float* __restrict__ adj,
    const float* __restrict__ W, const float* __restrict__ a,
    float* __restrict__ h, float* __restrict__ attn_src,
    float* __restrict__ attn_tgt,
    unsigned short* __restrict__ nbrs, int* __restrict__ deg)
{
    __shared__ f4 xs4[64][32];        // x tile, XOR-swizzled along kq (32KB)
    __shared__ float red_s[4][64];    // cross-wave attn_src partials
    __shared__ float red_t[4][64];
    __shared__ int wsum[4];

    const int t = threadIdx.x;

    if (blockIdx.x < GEMM_BLOCKS) {
        const int rb = blockIdx.x >> 2;        // row block 0..63
        const int cb = blockIdx.x & 3;         // col block == head
        const int row0 = rb * 64;
        const int tc4 = (t >> 4) * 4;          // this thread's 4 cols (within head)
        const int c0 = cb * 64 + tc4;
        const int tr = t & 15;                 // row group (rows tr*4 .. tr*4+3)

        // ---- stage x tile (64 rows x 128 k), swizzled: xs4[r][kq ^ (r>>2 & 7)]
        {
            const f4* xg = reinterpret_cast<const f4*>(x) + (size_t)row0 * 32;
            const int kq = t & 31;
            #pragma unroll
            for (int it = 0; it < 8; ++it) {
                const int r = it * 8 + (t >> 5);
                xs4[r][kq ^ ((r >> 2) & 7)] = xg[r * 32 + kq];
            }
        }
        __syncthreads();

        f4 acc[4] = {};   // acc[j] = float4 over 4 cols, j = row within group

        for (int kq = 0; kq < 32; ++kq) {      // 4 k's per iteration
            f4 wv[4];                          // W[4k+kk][c0..c0+3], per-lane distinct
            #pragma unroll
            for (int kk = 0; kk < 4; ++kk)
                wv[kk] = *reinterpret_cast<const f4*>(W + (kq * 4 + kk) * HID + c0);
            f4 xv[4];                          // xs[tr*4+j][4kq..4kq+3]
            #pragma unroll
            for (int j = 0; j < 4; ++j)
                xv[j] = xs4[tr * 4 + j][kq ^ (tr & 7)];
            #pragma unroll
            for (int kk = 0; kk < 4; ++kk)
                #pragma unroll
                for (int j = 0; j < 4; ++j)
                    acc[j] += xv[j][kk] * wv[kk];
        }

        // ---- write h (f32) ----
        #pragma unroll
        for (int j = 0; j < 4; ++j) {
            const int row = row0 + tr * 4 + j;
            *reinterpret_cast<f4*>(h + (size_t)row * HID + c0) = acc[j];
        }

        // ---- fused attn reductions: dot with a_src/a_tgt, reduce over 16 tc ----
        const f4 asv = *reinterpret_cast<const f4*>(a + cb * 2 * OUT_FEAT + tc4);
        const f4 atv = *reinterpret_cast<const f4*>(a + cb * 2 * OUT_FEAT + OUT_FEAT + tc4);
        const int wv_id = t >> 6;
        #pragma unroll
        for (int j = 0; j < 4; ++j) {
            float s = acc[j][0] * asv[0] + acc[j][1] * asv[1]
                    + acc[j][2] * asv[2] + acc[j][3] * asv[3];
            float g = acc[j][0] * atv[0] + acc[j][1] * atv[1]
                    + acc[j][2] * atv[2] + acc[j][3] * atv[3];
            s += __shfl_xor(s, 16, 64); s += __shfl_xor(s, 32, 64);
            g += __shfl_xor(g, 16, 64); g += __shfl_xor(g, 32, 64);
            if (((t >> 4) & 3) == 0) {          // one rep per (wave, tr)
                red_s[wv_id][tr * 4 + j] = s;
                red_t[wv_id][tr * 4 + j] = g;
            }
        }
        __syncthreads();
        if (t < 64) {
            const float s = red_s[0][t] + red_s[1][t] + red_s[2][t] + red_s[3][t];
            const float g = red_t[0][t] + red_t[1][t] + red_t[2][t] + red_t[3][t];
            attn_src[(row0 + t) * NHEAD + cb] = s;
            attn_tgt[(row0 + t) * NHEAD + cb] = g;
        }
    } else {
        // ---- adj scan: node i, build neighbor list (+ self loop) ----
        const int i = blockIdx.x - GEMM_BLOCKS;
        const int lane = t & 63;
        const int wv = t >> 6;

        const float4* arow = reinterpret_cast<const float4*>(adj + (size_t)i * N_NODES);
        unsigned mask16 = 0;
        #pragma unroll
        for (int u = 0; u < 4; ++u) {
            float4 v = arow[u * 256 + t];
            int jb = u * 1024 + t * 4;
            if (v.x != 0.f || (jb + 0) == i) mask16 |= 1u << (u * 4 + 0);
            if (v.y != 0.f || (jb + 1) == i) mask16 |= 1u << (u * 4 + 1);
            if (v.z != 0.f || (jb + 2) == i) mask16 |= 1u << (u * 4 + 2);
            if (v.w != 0.f || (jb + 3) == i) mask16 |= 1u << (u * 4 + 3);
        }
        int cnt = __popc(mask16);

        int incl = cnt;
        #pragma unroll
        for (int d = 1; d < 64; d <<= 1) {
            int u2 = __shfl_up(incl, d, 64);
            if (lane >= d) incl += u2;
        }
        if (lane == 63) wsum[wv] = incl;
        __syncthreads();
        int base = 0;
        #pragma unroll
        for (int w = 0; w < 4; ++w) base += (w < wv) ? wsum[w] : 0;
        int total = wsum[0] + wsum[1] + wsum[2] + wsum[3];
        if (total > MAXC) total = MAXC;   // safety; cannot trip at 1% density
        int off = base + incl - cnt;

        unsigned m = mask16;
        unsigned short* nl = nbrs + (size_t)i * MAXC;
        while (m) {
            int b = __ffs((int)m) - 1;
            m &= m - 1;
            int j = ((b >> 2) * 1024) + t * 4 + (b & 3);
            if (off < MAXC) nl[off] = (unsigned short)j;
            ++off;
        }
        if (t == 0) deg[i] = total;
    }
}

// ---------------------------------------------------------------------------
// Kernel 2: per node i — softmax over neighbor list + aggregation
// (4 neighbors / iteration, float4 per lane). Wave wv owns head wv.
// ---------------------------------------------------------------------------
__global__ __launch_bounds__(256) void k_agg(
    const unsigned short* __restrict__ nbrs, const int* __restrict__ deg,
    const float* __restrict__ h, const float* __restrict__ attn_src,
    const float* __restrict__ attn_tgt, float* __restrict__ out)
{
    __shared__ float p[NHEAD][MAXC];
    __shared__ unsigned short nl[MAXC];

    const int i = blockIdx.x;
    const int t = threadIdx.x;
    const int lane = t & 63;
    const int head = t >> 6;

    const int d = deg[i];
    nl[t] = (t < d) ? nbrs[(size_t)i * MAXC + t] : (unsigned short)0;
    __syncthreads();

    // ---- softmax (wave-local per head) ----
    const float srcv = attn_src[i * NHEAD + head];
    const int rnd = (d + 3) & ~3;
    float lmax = -1e30f;
    for (int idx = lane; idx < rnd; idx += 64) {
        if (idx < d) {
            float e = srcv + attn_tgt[nl[idx] * NHEAD + head];
            e = (e > 0.f) ? e : NEG_SLOPE * e;
            p[head][idx] = e;
            lmax = fmaxf(lmax, e);
        } else {
            p[head][idx] = 0.f;   // padding consumed with weight 0 below
        }
    }
    #pragma unroll
    for (int s = 32; s; s >>= 1) lmax = fmaxf(lmax, __shfl_xor(lmax, s, 64));
    float ssum = 0.f;
    for (int idx = lane; idx < d; idx += 64) {
        float pe = __expf(p[head][idx] - lmax);
        p[head][idx] = pe;
        ssum += pe;
    }
    #pragma unroll
    for (int s = 32; s; s >>= 1) ssum += __shfl_xor(ssum, s, 64);
    const float inv = 1.0f / ssum;   // d >= 1 always (self loop)

    // ---- aggregation: 4 neighbors per iteration ----
    const int g  = lane >> 4;        // neighbor sub-slot 0..3
    const int f4i = lane & 15;       // float4 feature chunk 0..15
    const float* hbase = h + head * OUT_FEAT + f4i * 4;
    float4 acc = {0.f, 0.f, 0.f, 0.f};
    for (int idx4 = 0; idx4 < d; idx4 += 4) {
        const int j   = nl[idx4 + g];          // LDS broadcast (pad -> 0)
        const float pw = p[head][idx4 + g];    // pad -> 0
        const float4 hv = *reinterpret_cast<const float4*>(hbase + (size_t)j * HID);
        acc.x += pw * hv.x; acc.y += pw * hv.y;
        acc.z += pw * hv.z; acc.w += pw * hv.w;
    }
    #pragma unroll
    for (int s = 16; s <= 32; s <<= 1) {
        acc.x += __shfl_xor(acc.x, s, 64);
        acc.y += __shfl_xor(acc.y, s, 64);
        acc.z += __shfl_xor(acc.z, s, 64);
        acc.w += __shfl_xor(acc.w, s, 64);
    }
    if (g == 0) {
        float4 o = {acc.x * inv, acc.y * inv, acc.z * inv, acc.w * inv};
        *reinterpret_cast<float4*>(out + (size_t)i * HID + head * OUT_FEAT + f4i * 4) = o;
    }
}

// ---------------------------------------------------------------------------
extern "C" void kernel_launch(void* const* d_in, const int* in_sizes, int n_in,
                              void* d_out, int out_size, void* d_ws, size_t ws_size,
                              hipStream_t stream)
{
    const float* x   = (const float*)d_in[0];   // (4096,128)
    const float* adj = (const float*)d_in[1];   // (4096,4096)
    const float* W   = (const float*)d_in[2];   // (128,256)
    const float* a   = (const float*)d_in[3];   // (4,128)
    float* out = (float*)d_out;                 // (4096,256)

    char* ws = (char*)d_ws;
    float* h         = (float*)ws;                                  // 4 MB
    float* attn_src  = (float*)(ws + (size_t)N_NODES * HID * 4);    // 64 KB
    float* attn_tgt  = attn_src + (size_t)N_NODES * NHEAD;          // 64 KB
    unsigned short* nbrs = (unsigned short*)(attn_tgt + (size_t)N_NODES * NHEAD); // 2 MB
    int* deg         = (int*)(nbrs + (size_t)N_NODES * MAXC);       // 16 KB

    k_prep<<<GEMM_BLOCKS + N_NODES, 256, 0, stream>>>(
        x, adj, W, a, h, attn_src, attn_tgt, nbrs, deg);
    k_agg<<<N_NODES, 256, 0, stream>>>(nbrs, deg, h, attn_src, attn_tgt, out);
}